// Round 8
// baseline (298.654 us; speedup 1.0000x reference)
//
#include <hip/hip_runtime.h>
#include <hip/hip_bf16.h>
#include <cstdint>

// Problem constants
#define DM   1024        // d_model
#define NH   16          // heads
#define DK   64          // head dim
#define BB   4           // batch
#define SS   2048        // seq
#define MTOT (BB * SS)   // 8192 tokens
#define PAD  68          // attn LDS row stride (u16): 136B = 2-bank skew -> conflict-free frags

typedef short short8 __attribute__((ext_vector_type(8)));
typedef float f32x4  __attribute__((ext_vector_type(4)));
using u16 = unsigned short;

// bf16 <-> f32 (RNE, finite values only)
__device__ inline u16 f2b(float f) {
    union { float f; unsigned int u; } v; v.f = f;
    unsigned int u = v.u;
    u += 0x7fffu + ((u >> 16) & 1u);
    return (u16)(u >> 16);
}
// truncating pack (1 VALU): P in [0,128], downward bias <= 2^-8 rel — fine
__device__ inline u16 f2b_trunc(float f) {
    union { float f; unsigned int u; } v; v.f = f;
    return (u16)(v.u >> 16);
}
__device__ inline float b2f(u16 s) {
    union { unsigned int u; float f; } v; v.u = ((unsigned int)s) << 16;
    return v.f;
}

// async global->LDS, 16B per lane. LDS dest = wave-uniform base + lane*16.
__device__ inline void load_lds16(const u16* g, u16* l) {
    __builtin_amdgcn_global_load_lds(
        (const __attribute__((address_space(1))) unsigned int*)g,
        (__attribute__((address_space(3))) unsigned int*)l, 16, 0, 0);
}

// originals + converted-buffer pointers, passed by value to kernels
struct CvtPtrs {
    const void *x, *Wq, *Wk, *Wv, *Wo, *bq, *bk, *bv, *bo;
    u16 *xb, *Wqb, *Wkb, *Wvb, *Wob, *bqb, *bkb, *bvb, *bob;
};

// ---------------------------------------------------------------------------
// Fused dtype-detect + conversion (unchanged from R7).
// ---------------------------------------------------------------------------
__global__ void convert_all(CvtPtrs p, int* __restrict__ flag)
{
    __shared__ int cnt;
    if (threadIdx.x == 0) cnt = 0;
    __syncthreads();
    int c = 0;
    for (int i = threadIdx.x; i < 512; i += 256) {
        const int e = (((const u16*)p.x)[i] >> 7) & 0xFF;
        if (e >= 100 && e <= 140) c++;
    }
    atomicAdd(&cnt, c);
    __syncthreads();
    const int isbf = (cnt >= 420) ? 1 : 0;
    if (blockIdx.x == 0 && threadIdx.x == 0) *flag = isbf;
    if (isbf) return;   // already bf16 — nothing to convert

    const size_t E  = (size_t)MTOT * DM;   // 2^23
    const size_t W1 = (size_t)DM * DM;     // 2^20
    const size_t i = ((size_t)blockIdx.x * blockDim.x + threadIdx.x) * 8;
    const float* s; u16* d; size_t off;
    if (i < E) {
        s = (const float*)p.x; d = p.xb; off = i;
    } else {
        size_t j = i - E;
        if (j < (W1 << 2)) {
            const int w = (int)(j >> 20); off = j & (W1 - 1);
            const float* ss[4] = {(const float*)p.Wq, (const float*)p.Wk,
                                  (const float*)p.Wv, (const float*)p.Wo};
            u16* dd[4] = {p.Wqb, p.Wkb, p.Wvb, p.Wob};
            s = ss[w]; d = dd[w];
        } else {
            j -= (W1 << 2);
            if (j >= 4 * DM) return;
            const int w = (int)(j >> 10); off = j & (DM - 1);
            const float* ss[4] = {(const float*)p.bq, (const float*)p.bk,
                                  (const float*)p.bv, (const float*)p.bo};
            u16* dd[4] = {p.bqb, p.bkb, p.bvb, p.bob};
            s = ss[w]; d = dd[w];
        }
    }
    const float4 f0 = *(const float4*)(s + off);
    const float4 f1 = *(const float4*)(s + off + 4);
    u16 tmp[8] = {f2b(f0.x), f2b(f0.y), f2b(f0.z), f2b(f0.w),
                  f2b(f1.x), f2b(f1.y), f2b(f1.z), f2b(f1.w)};
    *(int4*)(d + off) = *(const int4*)tmp;
}

// ---------------------------------------------------------------------------
// NT GEMM body, 2-WAVE variant: block = 128 threads, tile 128x128, BK=64.
// Wave w owns a 64m x 128n tile (4 m-frags x 8 n-frags, acc[4][8]).
// LDS reads per wave-iter: A 8KB + B 16KB for 128 MFMAs (0.19 KB/MFMA vs
// 0.5 in the 4-wave 64x64 layout) -> lifts the LDS-read-BW cap.
// Same XOR chunk swizzle as R7 (0 conflicts): LDS pos p of row r holds
// global chunk p ^ (r&7); staging lane l fetches chunk (l&7)^(l>>3).
// ---------------------------------------------------------------------------
__device__ __forceinline__
void gemm_body2(const u16* __restrict__ A, const u16* __restrict__ Bw,
                const u16* __restrict__ bias, void* __restrict__ out,
                int mode, float scale, int isbf, int m0, int n0,
                u16 (*As)[64], u16 (*Bs)[64])
{
    const int tid  = threadIdx.x;          // 0..127
    const int wave = tid >> 6;             // 0..1
    const int lane = tid & 63;

    const int lm   = lane & 15;
    const int quad = lane >> 4;
    const int rq   = quad * 4;

    // staging: 8 instrs per matrix per wave; instr c covers rows 8w+16c+(l>>3)
    const int lrow   = lane >> 3;
    const int lchunk = (lane & 7) ^ lrow;
    const u16* gA = A  + (size_t)(m0 + 8*wave + lrow) * DM + lchunk * 8;
    const u16* gB = Bw + (size_t)(n0 + 8*wave + lrow) * DM + lchunk * 8;
    u16* ldsA = (u16*)((char*)&As[0][0] + wave * 1024);
    u16* ldsB = (u16*)((char*)&Bs[0][0] + wave * 1024);

    f32x4 acc[4][8] = {};

    for (int k0 = 0; k0 < DM; k0 += 64) {
        __syncthreads();                    // prev tile reads done
#pragma unroll
        for (int c = 0; c < 8; c++) {
            load_lds16(gA + (size_t)c*16*DM + k0, (u16*)((char*)ldsA + c*2048));
            load_lds16(gB + (size_t)c*16*DM + k0, (u16*)((char*)ldsB + c*2048));
        }
        __syncthreads();                    // vmcnt(0) drained -> visible

#pragma unroll
        for (int ks = 0; ks < 2; ks++) {
            const int ca = ((ks*4 + quad) ^ (lm & 7)) * 8;   // swizzled col (u16)
            short8 af[4], bf[8];
#pragma unroll
            for (int i = 0; i < 4; i++) af[i] = *(const short8*)(&As[64*wave + 16*i + lm][ca]);
#pragma unroll
            for (int j = 0; j < 8; j++) bf[j] = *(const short8*)(&Bs[16*j + lm][ca]);
#pragma unroll
            for (int i = 0; i < 4; i++)
#pragma unroll
                for (int j = 0; j < 8; j++)
                    acc[i][j] = __builtin_amdgcn_mfma_f32_16x16x32_bf16(af[i], bf[j], acc[i][j], 0, 0, 0);
        }
    }

    // epilogue: rows m0+64w+16i+rq+r, cols n0+16j+lm
#pragma unroll
    for (int j = 0; j < 8; j++) {
        const int col = n0 + 16*j + lm;
        const float bv = b2f(bias[col]);
        const int h = col >> 6, d = col & 63;
#pragma unroll
        for (int i = 0; i < 4; i++) {
            if (mode == 2) {
                const int row0 = m0 + 64*wave + 16*i + rq;
                const int b = row0 >> 11, s = row0 & 2047;
                u16 tmp[4];
#pragma unroll
                for (int r = 0; r < 4; r++)
                    tmp[r] = f2b((acc[i][j][r] + bv) * scale);
                const size_t idx = (((size_t)(b*NH + h) * DK) + d) * SS + s;
                *(uint2*)(&((u16*)out)[idx]) = *(const uint2*)tmp;
            } else {
#pragma unroll
                for (int r = 0; r < 4; r++) {
                    const int row = m0 + 64*wave + 16*i + rq + r;
                    const float v = (acc[i][j][r] + bv) * scale;
                    if (mode == 0) {
                        const size_t idx = (size_t)row * DM + col;
                        if (isbf) ((u16*)out)[idx] = f2b(v);
                        else      ((float*)out)[idx] = v;
                    } else {
                        const int b = row >> 11, s = row & 2047;
                        const size_t idx = (((size_t)(b*NH + h) * SS) + s) * DK + d;
                        ((u16*)out)[idx] = f2b(v);
                    }
                }
            }
        }
    }
}

// ---------------------------------------------------------------------------
// NT GEMM body, 4-WAVE variant (R7, proven) — used by gemm_out where 512
// blocks at 2/CU need the extra waves for latency hiding.
// ---------------------------------------------------------------------------
__device__ __forceinline__
void gemm_body4(const u16* __restrict__ A, const u16* __restrict__ Bw,
                const u16* __restrict__ bias, void* __restrict__ out,
                int mode, float scale, int isbf, int m0, int n0,
                u16 (*As)[64], u16 (*Bs)[64])
{
    const int tid  = threadIdx.x;
    const int wave = tid >> 6;
    const int lane = tid & 63;
    const int wm = (wave >> 1) * 64;
    const int wn = (wave & 1) * 64;

    const int lm   = lane & 15;
    const int quad = lane >> 4;
    const int rq   = quad * 4;

    const int lrow   = lane >> 3;
    const int lchunk = (lane & 7) ^ lrow;
    const u16* gA = A  + (size_t)(m0 + 8*wave + lrow) * DM + lchunk * 8;
    const u16* gB = Bw + (size_t)(n0 + 8*wave + lrow) * DM + lchunk * 8;
    u16* ldsA = (u16*)((char*)&As[0][0] + wave * 1024);
    u16* ldsB = (u16*)((char*)&Bs[0][0] + wave * 1024);

    f32x4 acc[4][4] = {};

    for (int k0 = 0; k0 < DM; k0 += 64) {
        __syncthreads();
#pragma unroll
        for (int c = 0; c < 4; c++) {
            load_lds16(gA + (size_t)c*32*DM + k0, (u16*)((char*)ldsA + c*4096));
            load_lds16(gB + (size_t)c*32*DM + k0, (u16*)((char*)ldsB + c*4096));
        }
        __syncthreads();

#pragma unroll
        for (int ks = 0; ks < 2; ks++) {
            const int ca = ((ks*4 + quad) ^ (lm & 7)) * 8;
            short8 af[4], bf[4];
#pragma unroll
            for (int i = 0; i < 4; i++) af[i] = *(const short8*)(&As[wm + 16*i + lm][ca]);
#pragma unroll
            for (int j = 0; j < 4; j++) bf[j] = *(const short8*)(&Bs[wn + 16*j + lm][ca]);
#pragma unroll
            for (int i = 0; i < 4; i++)
#pragma unroll
                for (int j = 0; j < 4; j++)
                    acc[i][j] = __builtin_amdgcn_mfma_f32_16x16x32_bf16(af[i], bf[j], acc[i][j], 0, 0, 0);
        }
    }

#pragma unroll
    for (int j = 0; j < 4; j++) {
        const int col = n0 + wn + 16*j + lm;
        const float bv = b2f(bias[col]);
#pragma unroll
        for (int i = 0; i < 4; i++) {
#pragma unroll
            for (int r = 0; r < 4; r++) {
                const int row = m0 + wm + 16*i + rq + r;
                const float v = (acc[i][j][r] + bv) * scale;
                const size_t idx = (size_t)row * DM + col;
                if (isbf) ((u16*)out)[idx] = f2b(v);
                else      ((float*)out)[idx] = v;
            }
        }
    }
}

// Fused QKV projection, 1536 blocks x 128 threads, XCD-aware mapping.
__global__ __launch_bounds__(128, 2)
void gemm_qkv(CvtPtrs p, u16* __restrict__ Qb, u16* __restrict__ Kb,
              u16* __restrict__ Vb, float qscale, const int* __restrict__ flag)
{
    __shared__ __align__(16) u16 As[128][64];
    __shared__ __align__(16) u16 Bs[128][64];
    const int id  = blockIdx.x;
    const int xcd = id & 7;
    const int j   = id >> 3;               // 0..191
    const int m0  = (xcd * 8 + (j & 7)) * 128;
    const int n0  = ((j >> 3) & 7) * 128;
    const int z   = j >> 6;                // 0..2
    const int isbf = *flag;
    const u16* A = isbf ? (const u16*)p.x : p.xb;
    const u16* Bw, *bias; u16* out;
    if (z == 0)      { Bw = isbf ? (const u16*)p.Wq : p.Wqb; bias = isbf ? (const u16*)p.bq : p.bqb; out = Qb; }
    else if (z == 1) { Bw = isbf ? (const u16*)p.Wk : p.Wkb; bias = isbf ? (const u16*)p.bk : p.bkb; out = Kb; }
    else             { Bw = isbf ? (const u16*)p.Wv : p.Wvb; bias = isbf ? (const u16*)p.bv : p.bvb; out = Vb; }
    const int mode  = (z == 2) ? 2 : 1;
    const float sc  = (z == 0) ? qscale : 1.0f;
    gemm_body2(A, Bw, bias, out, mode, sc, 1, m0, n0, As, Bs);
}

// Output projection (mode 0), 512 blocks x 256 threads, XCD-aware (R7 body).
__global__ __launch_bounds__(256)
void gemm_out(const u16* __restrict__ Ab, CvtPtrs p, void* __restrict__ out,
              const int* __restrict__ flag)
{
    __shared__ __align__(16) u16 As[128][64];
    __shared__ __align__(16) u16 Bs[128][64];
    const int id  = blockIdx.x;
    const int xcd = id & 7;
    const int j   = id >> 3;               // 0..63
    const int m0  = (xcd * 8 + (j & 7)) * 128;
    const int n0  = (j >> 3) * 128;
    const int isbf = *flag;
    const u16* Bw   = isbf ? (const u16*)p.Wo : p.Wob;
    const u16* bias = isbf ? (const u16*)p.bo : p.bob;
    gemm_body4(Ab, Bw, bias, out, 0, 1.0f, isbf, m0, n0, As, Bs);
}

// ---------------------------------------------------------------------------
// Streaming-softmax causal attention (unchanged from R7).
// ---------------------------------------------------------------------------
__global__ __launch_bounds__(256)
void attn_causal(const u16* __restrict__ Q, const u16* __restrict__ K,
                 const u16* __restrict__ VT, u16* __restrict__ O)
{
    __shared__ __align__(16) u16 Ks[2][64][PAD];
    __shared__ __align__(16) u16 Vs[2][64][PAD];   // V^T tiles: [d][k]
    __shared__ __align__(16) u16 Ps[128][PAD];

    const int tid  = threadIdx.x;
    const int wave = tid >> 6;
    const int lane = tid & 63;
    const int qx = blockIdx.x;             // 0..7
    const int h = blockIdx.y, b = blockIdx.z;
    const int bh = b * NH + h;

    const u16* Kg = K  + (size_t)bh * SS * DK;
    const u16* Vg = VT + (size_t)bh * DK * SS;

    const int srow = tid >> 3;        // 0..31 (two passes: +0, +32)
    const int scol = (tid & 7) * 8;   // 0..56
    const int lm = lane & 15, quad = lane >> 4, kq = quad * 8, rq = quad * 4;

#pragma unroll
    for (int seg = 0; seg < 2; seg++) {
        const int qt = seg ? (15 - qx) : qx;
        const int q0 = qt * 128;
        const int nt = 2 * (qt + 1);
        const u16* Qg = Q + ((size_t)bh * SS + q0) * DK;

        short8 qa[2][2];
#pragma unroll
        for (int mi = 0; mi < 2; mi++)
#pragma unroll
            for (int ks = 0; ks < 2; ks++)
                qa[mi][ks] = *(const short8*)(&Qg[(size_t)(32*wave + 16*mi + lm) * DK + ks*32 + kq]);

        int4 kv0 = *(const int4*)(&Kg[(size_t)srow * DK + scol]);
        int4 kv1 = *(const int4*)(&Kg[(size_t)(srow + 32) * DK + scol]);
        int4 vv0 = *(const int4*)(&Vg[(size_t)srow * SS + scol]);
        int4 vv1 = *(const int4*)(&Vg[(size_t)(srow + 32) * SS + scol]);
        *(int4*)(&Ks[0][srow][scol])      = kv0;
        *(int4*)(&Ks[0][srow + 32][scol]) = kv1;
        *(int4*)(&Vs[0][srow][scol])      = vv0;
        *(int4*)(&Vs[0][srow + 32][scol]) = vv1;
        __syncthreads();

        kv0 = *(const int4*)(&Kg[(size_t)(64 + srow) * DK + scol]);
        kv1 = *(const int4*)(&Kg[(size_t)(64 + srow + 32) * DK + scol]);
        vv0 = *(const int4*)(&Vg[(size_t)srow * SS + 64 + scol]);
        vv1 = *(const int4*)(&Vg[(size_t)(srow + 32) * SS + 64 + scol]);

        f32x4 o[2][4] = {};
        float lacc[2][4] = {};

        for (int t = 0; t < nt; t++) {
            const int buf = t & 1;
            const int k0 = 64 * t;

            f32x4 sc[2][4] = {};
#pragma unroll
            for (int ks = 0; ks < 2; ks++)
#pragma unroll
                for (int j = 0; j < 4; j++) {
                    const short8 bfr = *(const short8*)(&Ks[buf][16*j + lm][ks*32 + kq]);
                    sc[0][j] = __builtin_amdgcn_mfma_f32_16x16x32_bf16(qa[0][ks], bfr, sc[0][j], 0, 0, 0);
                    sc[1][j] = __builtin_amdgcn_mfma_f32_16x16x32_bf16(qa[1][ks], bfr, sc[1][j], 0, 0, 0);
                }

            if (k0 + 63 > q0 + 32*wave) {
#pragma unroll
                for (int mi = 0; mi < 2; mi++)
#pragma unroll
                    for (int j = 0; j < 4; j++)
#pragma unroll
                        for (int r = 0; r < 4; r++)
                            if (k0 + 16*j + lm > q0 + 32*wave + 16*mi + rq + r)
                                sc[mi][j][r] = -1e30f;
            }

#pragma unroll
            for (int mi = 0; mi < 2; mi++)
#pragma unroll
                for (int j = 0; j < 4; j++)
#pragma unroll
                    for (int r = 0; r < 4; r++) {
                        const float pv = __builtin_amdgcn_exp2f(sc[mi][j][r]);
                        lacc[mi][r] += pv;
                        Ps[32*wave + 16*mi + rq + r][16*j + lm] = f2b_trunc(pv);
                    }

#pragma unroll
            for (int ks = 0; ks < 2; ks++) {
                const short8 pa0 = *(const short8*)(&Ps[32*wave + lm][ks*32 + kq]);
                const short8 pa1 = *(const short8*)(&Ps[32*wave + 16 + lm][ks*32 + kq]);
#pragma unroll
                for (int j = 0; j < 4; j++) {
                    const short8 vfr = *(const short8*)(&Vs[buf][16*j + lm][ks*32 + kq]);
                    o[0][j] = __builtin_amdgcn_mfma_f32_16x16x32_bf16(pa0, vfr, o[0][j], 0, 0, 0);
                    o[1][j] = __builtin_amdgcn_mfma_f32_16x16x32_bf16(pa1, vfr, o[1][j], 0, 0, 0);
                }
            }

            if (t + 1 < nt) {
                const int nb = buf ^ 1;
                *(int4*)(&Ks[nb][srow][scol])      = kv0;
                *(int4*)(&Ks[nb][srow + 32][scol]) = kv1;
                *(int4*)(&Vs[nb][srow][scol])      = vv0;
                *(int4*)(&Vs[nb][srow + 32][scol]) = vv1;
                if (t + 2 < nt) {
                    const int kn = 64 * (t + 2);
                    kv0 = *(const int4*)(&Kg[(size_t)(kn + srow) * DK + scol]);
                    kv1 = *(const int4*)(&Kg[(size_t)(kn + srow + 32) * DK + scol]);
                    vv0 = *(const int4*)(&Vg[(size_t)srow * SS + kn + scol]);
                    vv1 = *(const int4*)(&Vg[(size_t)(srow + 32) * SS + kn + scol]);
                }
            }
            __syncthreads();
        }

#pragma unroll
        for (int mi = 0; mi < 2; mi++)
#pragma unroll
            for (int r = 0; r < 4; r++) {
                float v = lacc[mi][r];
#pragma unroll
                for (int off = 1; off < 16; off <<= 1)
                    v += __shfl_xor(v, off, 64);
                const float inv = 1.f / v;
                const size_t rowg = (size_t)b * SS + q0 + 32*wave + 16*mi + rq + r;
#pragma unroll
                for (int j = 0; j < 4; j++)
                    O[rowg * DM + h*DK + 16*j + lm] = f2b(o[mi][j][r] * inv);
            }
    }
}

extern "C" void kernel_launch(void* const* d_in, const int* in_sizes, int n_in,
                              void* d_out, int out_size, void* d_ws, size_t ws_size,
                              hipStream_t stream)
{
    (void)in_sizes; (void)n_in; (void)out_size; (void)ws_size;

    int* flag = (int*)d_ws;
    u16* ws = (u16*)((char*)d_ws + 16);

    const size_t E  = (size_t)MTOT * DM;
    const size_t W1 = (size_t)DM * DM;
    u16* xb  = ws;                 // [B,S,DM] bf16; reused as Ab later
    u16* Wqb = ws + E;
    u16* Wkb = Wqb + W1;
    u16* Wvb = Wkb + W1;
    u16* Wob = Wvb + W1;
    u16* bqb = Wob + W1;
    u16* bkb = bqb + DM;
    u16* bvb = bkb + DM;
    u16* bob = bvb + DM;
    u16* Qb  = bob + DM;           // [B,H,S,dk] (pre-scaled)
    u16* Kb  = Qb + E;             // [B,H,S,dk]
    u16* Vb  = Kb + E;             // [B,H,dk,S] (V^T)
    u16* Ab  = xb;                 // attention out [B,S,DM]; x dead by then

    CvtPtrs p;
    p.x = d_in[0];
    // d_in[1] = mask (int32) — causal, handled analytically
    p.Wq = d_in[2]; p.bq = d_in[3];
    p.Wk = d_in[4]; p.bk = d_in[5];
    p.Wv = d_in[6]; p.bv = d_in[7];
    p.Wo = d_in[8]; p.bo = d_in[9];
    p.xb = xb;
    p.Wqb = Wqb; p.Wkb = Wkb; p.Wvb = Wvb; p.Wob = Wob;
    p.bqb = bqb; p.bkb = bkb; p.bvb = bvb; p.bob = bob;

    const int cvt_blocks = (int)((E + 4*W1 + 4*DM) / 2048);   // 6146
    convert_all<<<cvt_blocks, 256, 0, stream>>>(p, flag);

    const float qscale = 0.18033688011112042f;  // (1/sqrt(64)) * log2(e)

    gemm_qkv<<<1536, 128, 0, stream>>>(p, Qb, Kb, Vb, qscale, flag);
    attn_causal<<<dim3(SS/256, NH, BB), 256, 0, stream>>>(Qb, Kb, Vb, Ab);
    gemm_out<<<512, 256, 0, stream>>>(Ab, p, d_out, flag);
}